// Round 7
// baseline (867.202 us; speedup 1.0000x reference)
//
#include <hip/hip_runtime.h>

// SSIM loss, fused single pass, barrier-free, spill-free.
// [32,3,512,512] fp32 = 96 planes of 512x512. Each WAVE owns a 64x64 tile.
// Round-12: round-10 base (verified absmax 0.0, main 125us) + one-phase
// H-RESULT pipeline. Round-11's raw-tap vbuf[2][11] went to SCRATCH
// (WRITE_SIZE 48KB->1.1GB, 664us) -- rule #20. Fix: pipeline only the 5
// horizontal conv results in a named-field struct pair (Hp A/B), swapped
// via constexpr parity templates; no indexable arrays cross phases.
// Phase j:
//   1) DMA row j+6 -> ring slot (j+6)&7   (margin 6; RING=8)
//   2) s_waitcnt vmcnt(10)                (row j+1 complete; 5 rows in flight)
//   3) ds_read2 + h-conv row j+1 -> nxt   (masked by row validity, 0/1 mul;
//                                          branchless -> same basic block)
//   4) scatter row j from cur (independent of step 3 -> scheduler interleaves
//      33 scatter FMAs under the ds_read latency)
//   5) emit l=j-10 (wave-uniform), reset slot
// Accumulation order identical to round-10 (OOB rows contribute exact +0)
// -> expect absmax 0.0.

#define IMG_H   512
#define IMG_W   512
#define TH      64          // tile rows/cols per wave
#define LROW    160         // floats per LDS row-slot: p[0..79] | t[80..159]
#define RING    8           // ring slots (rows j+1..j+6 live)
#define SSIM_C1 1e-4f
#define SSIM_C2 9e-4f

typedef float v2f __attribute__((ext_vector_type(2)));

// Cross-phase pipeline state: horizontal conv results of one input row.
struct Hp { v2f h01; v2f h23; float hpt; };

// Gaussian taps, sigma=1.5, window 11.
__device__ constexpr float G[11] = {
    0.00102838f, 0.00759879f, 0.03600078f, 0.10936070f, 0.21300563f,
    0.26601180f,
    0.21300563f, 0.10936070f, 0.03600078f, 0.00759879f, 0.00102838f
};

// Async 16B/lane global->LDS. Global addr is per-lane; LDS dest is
// wave-uniform base + lane*16 (m97/m104).
__device__ __forceinline__ void gload16(const float* g, float* l) {
    __builtin_amdgcn_global_load_lds(
        (const __attribute__((address_space(1))) float*)g,
        (__attribute__((address_space(3))) float*)l, 16, 0, 0);
}

template<int PH>
__device__ __forceinline__ void phase_body(const float* __restrict__ pplw,
                                           const float* __restrict__ tplw,
                                           int r0, int j0, int lane4,
                                           float (*B)[LROW],
                                           int lane, bool lv,
                                           Hp& cur, Hp& nxt,
                                           v2f (&acc01)[11], v2f (&acc23)[11],
                                           float (&accpt)[11], float& lsum) {
    const int j = j0 + PH;

    // ---- 1) issue async dwordx4 loads for row j+6 into slot (j+6)&7 ----
    // Row clamped so EVERY phase issues exactly 2 VMEM ops (vmcnt exact);
    // clamped-row data is finite and gets masked to 0 at the h stage.
    {
        const int rg  = r0 + j + 1;               // = (r0-5) + (j+6)
        const int rgc = min(max(rg, 0), IMG_H - 1);
        const int sI  = (j + 6) & (RING - 1);
        const float* ps = pplw + (size_t)rgc * IMG_W + lane4;  // per-lane
        const float* ts = tplw + (size_t)rgc * IMG_W + lane4;
        if (lv) {                                 // 18-20 lanes active
            gload16(ps, &B[sI][0]);               // p -> [0..79]
            gload16(ts, &B[sI][80]);              // t -> [80..159]
        }
    }

    // ---- 2) counted wait: rows j+2..j+6 (10 loads) stay in flight ----
    asm volatile("s_waitcnt vmcnt(10)" ::: "memory");

    // ---- 3) ds_read2 + horizontal conv of row j+1 -> nxt (masked) ----
    {
        const int sR = (j + 1) & (RING - 1);
        const float* Lb = &B[sR][lane + 3];
        v2f h01 = {0.f, 0.f};                     // {hp, ht}
        v2f h23 = {0.f, 0.f};                     // {hpp, htt}
        float hpt = 0.f;
#define CV(i) { const v2f wv = {G[i], G[i]};                                 \
                v2f v; v.x = Lb[i]; v.y = Lb[i + 80];                        \
                h01 = __builtin_elementwise_fma(wv, v, h01);                 \
                const v2f wab = wv * v;                                      \
                h23 = __builtin_elementwise_fma(wab, v, h23);                \
                hpt = fmaf(wab.x, v.y, hpt); }
        CV(0) CV(1) CV(2) CV(3) CV(4) CV(5) CV(6) CV(7) CV(8) CV(9) CV(10)
#undef CV
        const int grow = r0 - 4 + j;              // global row of j+1
        const float m  = (grow >= 0 && grow < IMG_H) ? 1.f : 0.f;
        const v2f mv = {m, m};
        nxt.h01 = h01 * mv;                       // OOB row -> exact 0
        nxt.h23 = h23 * mv;
        nxt.hpt = hpt * m;
    }

    // ---- 4) vertical scatter of row j from cur (h==0 if row OOB) ----
    // row j feeds outputs l = j-10..j, slot = l%11.
#define SCAT(s) { constexpr int m = ((s) - PH + 21) % 11;                    \
                  constexpr float w = G[10 - m];                             \
                  const v2f wv = {w, w};                                     \
                  acc01[s] = __builtin_elementwise_fma(wv, cur.h01, acc01[s]); \
                  acc23[s] = __builtin_elementwise_fma(wv, cur.h23, acc23[s]); \
                  accpt[s] = fmaf(w, cur.hpt, accpt[s]); }
    SCAT(0) SCAT(1) SCAT(2) SCAT(3) SCAT(4) SCAT(5)
    SCAT(6) SCAT(7) SCAT(8) SCAT(9) SCAT(10)
#undef SCAT

    // ---- 5) emit completed output row l = j-10 (slot (PH+1)%11), reset ----
    constexpr int SE = (PH + 1) % 11;
    const int l = j - 10;
    if (l >= 0 && l < TH) {                       // wave-uniform branch
        const float mp = acc01[SE].x, mt = acc01[SE].y;
        const float mpp = mp * mp, mtt = mt * mt, mpt = mp * mt;
        const float sp  = acc23[SE].x - mpp;
        const float st  = acc23[SE].y - mtt;
        const float spt = accpt[SE]   - mpt;
        const float num = (2.f * mpt + SSIM_C1) * (2.f * spt + SSIM_C2);
        const float den = (mpp + mtt + SSIM_C1) * (sp + st + SSIM_C2);
        lsum += num * __builtin_amdgcn_rcpf(den); // den >= C1*C2 > 0
    }
    acc01[SE] = (v2f){0.f, 0.f};
    acc23[SE] = (v2f){0.f, 0.f};
    accpt[SE] = 0.f;
}

template<int PH, int PAR>
__device__ __forceinline__ void phase(const float* __restrict__ pplw,
                                      const float* __restrict__ tplw,
                                      int r0, int j0, int lane4,
                                      float (*B)[LROW],
                                      int lane, bool lv,
                                      Hp& HA, Hp& HB,
                                      v2f (&acc01)[11], v2f (&acc23)[11],
                                      float (&accpt)[11], float& lsum) {
    if constexpr (((PH + PAR) & 1) == 0)
        phase_body<PH>(pplw, tplw, r0, j0, lane4, B, lane, lv,
                       HA, HB, acc01, acc23, accpt, lsum);
    else
        phase_body<PH>(pplw, tplw, r0, j0, lane4, B, lane, lv,
                       HB, HA, acc01, acc23, accpt, lsum);
}

__global__ __launch_bounds__(256, 4) void ssim_main(const float* __restrict__ pred,
                                                    const float* __restrict__ targ,
                                                    float* __restrict__ ws) {
    __shared__ float B[4][RING][LROW];    // [wave][slot][p|t]  = 20.0 KB
    __shared__ float wsum[4];

    const int tid  = threadIdx.x;
    const int lane = tid & 63;
    const int wid  = tid >> 6;

    // 6144 tiles = 8 col-strips x 8 row-bands x 96 planes; 4 waves/block.
    const int gt    = __builtin_amdgcn_readfirstlane(blockIdx.x * 4 + wid);
    const int c0    = (gt & 7) * TH;
    const int r0    = ((gt >> 3) & 7) * TH;
    const int plane = gt >> 6;
    // Window base: column c0-8 (16B-aligned since c0%64==0).
    const float* pplw = pred + (size_t)plane * (IMG_H * IMG_W) + (c0 - 8);
    const float* tplw = targ + (size_t)plane * (IMG_H * IMG_W) + (c0 - 8);

    float (*W)[LROW] = B[wid];

    // Lane covers window cols [4*lane, 4*lane+3] = global [c0-8+4*lane, +3].
    const int  lane4 = lane * 4;
    const int  gc0   = c0 - 8 + lane4;
    const bool lv    = (lane < 20) && (gc0 >= 0) && (gc0 <= IMG_W - 4);

    // Pre-zero LDS words of permanently masked lanes (edge strips only):
    // gload_lds never touches them, so they stay zero all kernel.
    if (lane < 20 && !lv) {
        #pragma unroll
        for (int s = 0; s < RING; ++s) {
            #pragma unroll
            for (int w = 0; w < 4; ++w) {
                W[s][lane4 + w]      = 0.f;       // p section
                W[s][80 + lane4 + w] = 0.f;       // t section
            }
        }
    }

    // Prologue: issue rows j=0..5 (global rows r0-5..r0, top-clamped) into
    // ring slots 0..5 = 12 VMEM ops.
    #pragma unroll
    for (int r = 0; r < 6; ++r) {
        const int rg  = max(r0 - 5 + r, 0);       // top clamp only (r0<=448)
        const float* ps = pplw + (size_t)rg * IMG_W + lane4;
        const float* ts = tplw + (size_t)rg * IMG_W + lane4;
        if (lv) {
            gload16(ps, &W[r][0]);
            gload16(ts, &W[r][80]);
        }
    }

    v2f   acc01[11];
    v2f   acc23[11];
    float accpt[11];
    #pragma unroll
    for (int s = 0; s < 11; ++s) {
        acc01[s] = (v2f){0.f, 0.f};
        acc23[s] = (v2f){0.f, 0.f};
        accpt[s] = 0.f;
    }

    Hp HA, HB;
    HA.h01 = (v2f){0.f, 0.f}; HA.h23 = (v2f){0.f, 0.f}; HA.hpt = 0.f;
    HB.h01 = (v2f){0.f, 0.f}; HB.h23 = (v2f){0.f, 0.f}; HB.hpt = 0.f;

    // Prologue pipeline fill: wait until row 0 complete (rows 1..5 = 10
    // loads in flight), then h-conv row 0 -> HA (masked by validity).
    asm volatile("s_waitcnt vmcnt(10)" ::: "memory");
    {
        const float* Lb = &W[0][lane + 3];
        v2f h01 = {0.f, 0.f};
        v2f h23 = {0.f, 0.f};
        float hpt = 0.f;
#define CV(i) { const v2f wv = {G[i], G[i]};                                 \
                v2f v; v.x = Lb[i]; v.y = Lb[i + 80];                        \
                h01 = __builtin_elementwise_fma(wv, v, h01);                 \
                const v2f wab = wv * v;                                      \
                h23 = __builtin_elementwise_fma(wab, v, h23);                \
                hpt = fmaf(wab.x, v.y, hpt); }
        CV(0) CV(1) CV(2) CV(3) CV(4) CV(5) CV(6) CV(7) CV(8) CV(9) CV(10)
#undef CV
        const float m = (r0 - 5 >= 0) ? 1.f : 0.f;
        const v2f mv = {m, m};
        HA.h01 = h01 * mv;
        HA.h23 = h23 * mv;
        HA.hpt = hpt * m;
    }

    float lsum = 0.f;

#define P(n, PAR) phase<n, PAR>(pplw, tplw, r0, j0, lane4, W, lane, lv, \
                                HA, HB, acc01, acc23, accpt, lsum);
#define CHNK(PAR) { P(0,PAR) P(1,PAR) P(2,PAR) P(3,PAR) P(4,PAR) P(5,PAR) \
                    P(6,PAR) P(7,PAR) P(8,PAR) P(9,PAR) P(10,PAR) }

    int j0 = 0;
    for (int c = 0; c < 3; ++c) {     // chunks 0..5: even+odd pairs
        CHNK(0)
        j0 += 11;
        CHNK(1)
        j0 += 11;
    }
    CHNK(0)                           // chunk 6 (j0 = 66, even)
#undef CHNK
#undef P

    // wave reduce -> one plain store per block into the workspace
    #pragma unroll
    for (int off = 32; off > 0; off >>= 1) lsum += __shfl_down(lsum, off);
    if (lane == 0) wsum[wid] = lsum;
    __syncthreads();
    if (tid == 0) ws[blockIdx.x] = wsum[0] + wsum[1] + wsum[2] + wsum[3];
}

__global__ __launch_bounds__(256) void ssim_finalize(const float* __restrict__ ws,
                                                     float* __restrict__ out) {
    __shared__ float wsum[4];
    const int tid  = threadIdx.x;
    const int lane = tid & 63;
    const int wid  = tid >> 6;
    float s = 0.f;
    #pragma unroll
    for (int i = 0; i < 6; ++i) s += ws[tid + 256 * i];   // 1536 = 6*256
    #pragma unroll
    for (int off = 32; off > 0; off >>= 1) s += __shfl_down(s, off);
    if (lane == 0) wsum[wid] = s;
    __syncthreads();
    if (tid == 0) {
        const float tot = wsum[0] + wsum[1] + wsum[2] + wsum[3];
        out[0] = 1.0f - tot * (1.0f / 25165824.0f);  // 1 - sum/(32*3*512*512)
    }
}

extern "C" void kernel_launch(void* const* d_in, const int* in_sizes, int n_in,
                              void* d_out, int out_size, void* d_ws, size_t ws_size,
                              hipStream_t stream) {
    (void)in_sizes; (void)n_in; (void)out_size; (void)ws_size;
    const float* pred = (const float*)d_in[0];
    const float* targ = (const float*)d_in[1];
    float* ws  = (float*)d_ws;          // 1536 floats of scratch
    float* out = (float*)d_out;

    ssim_main<<<dim3(1536), 256, 0, stream>>>(pred, targ, ws);
    ssim_finalize<<<1, 256, 0, stream>>>(ws, out);
}

// Round 8
// 254.176 us; speedup vs baseline: 3.4118x; 3.4118x over previous
//
#include <hip/hip_runtime.h>

// SSIM loss, fused single pass, barrier-free, spill-free.
// [32,3,512,512] fp32 = 96 planes of 512x512. Each WAVE owns a 64x64 tile.
// Round-13 == round-10 (verified absmax 0.0, main 125us) with ONE change:
//   __launch_bounds__(256, 4) -> (256, 2).
// Theory: VGPR_Count=40 < 55 live accumulator floats -> acc lives in AGPRs
// (scratch ruled out: would need >100 TB/s through L2). CDNA VALU can't
// touch AGPRs: every acc update = accvgpr_read + fma + accvgpr_write, i.e.
// scatter is ~143 inst/phase not 33 (+110/phase). 200 inst/phase x 77 x 2cy
// x 6 waves/SIMD = 77us VALU-busy = 0.62*125 -- matches VALUBusy 71%.
// (256,4) capped arch VGPRs at 512/4=128; (256,2) raises the cap to 256 so
// the allocator keeps acc in plain VGPRs (~110 used -> 4 waves/SIMD).
// Round-11/12 software-pipeline attempts: both exploded to scratch
// (WRITE_SIZE 1.1GB, 664/750us) -- abandoned.
// Structure (round-10): 8-slot LDS ring, distance-5 prefetch, s_waitcnt
// vmcnt(10) (never 0), global_load_lds dwordx4 per-lane addr + uniform LDS
// dest, merged p|t slot (ds_read2 pairs), pk dual-f32 conv/scatter, EXACT
// round-3 arithmetic.

#define IMG_H   512
#define IMG_W   512
#define TH      64          // tile rows/cols per wave
#define NCHUNK  7           // 7*11 = 77 row-phases (74 input rows needed)
#define LROW    160         // floats per LDS row-slot: p[0..79] | t[80..159]
#define RING    8           // ring slots (rows j..j+5 live)
#define SSIM_C1 1e-4f
#define SSIM_C2 9e-4f

typedef float v2f __attribute__((ext_vector_type(2)));

// Gaussian taps, sigma=1.5, window 11.
__device__ constexpr float G[11] = {
    0.00102838f, 0.00759879f, 0.03600078f, 0.10936070f, 0.21300563f,
    0.26601180f,
    0.21300563f, 0.10936070f, 0.03600078f, 0.00759879f, 0.00102838f
};

// Async 16B/lane global->LDS. Global addr is per-lane; LDS dest is
// wave-uniform base + lane*16 (m97/m104).
__device__ __forceinline__ void gload16(const float* g, float* l) {
    __builtin_amdgcn_global_load_lds(
        (const __attribute__((address_space(1))) float*)g,
        (__attribute__((address_space(3))) float*)l, 16, 0, 0);
}

template<int PH>
__device__ __forceinline__ void phase(const float* __restrict__ pplw,
                                      const float* __restrict__ tplw,
                                      int r0, int j0, int lane4,
                                      float (*B)[LROW],
                                      int lane, bool lv,
                                      v2f (&acc01)[11], v2f (&acc23)[11],
                                      float (&accpt)[11], float& lsum) {
    const int j = j0 + PH;

    // ---- issue async dwordx4 loads for row j+5 into ring slot (j+5)&7 ----
    // Row clamped so EVERY phase issues exactly 2 VMEM ops (vmcnt arithmetic
    // exact); clamped-row garbage never read (row-OOB phases skip conv).
    {
        const int rg  = r0 + j;                   // = (r0-5) + (j+5)
        const int rgc = min(max(rg, 0), IMG_H - 1);
        const int sI  = (j + 5) & (RING - 1);
        const float* ps = pplw + (size_t)rgc * IMG_W + lane4;  // per-lane
        const float* ts = tplw + (size_t)rgc * IMG_W + lane4;
        if (lv) {                                 // 18-20 lanes active
            gload16(ps, &B[sI][0]);               // p -> [0..79]
            gload16(ts, &B[sI][80]);              // t -> [80..159]
        }
    }

    // ---- counted wait: rows j+1..j+5 (10 loads) may stay in flight ----
    asm volatile("s_waitcnt vmcnt(10)" ::: "memory");

    // ---- horizontal 11-tap conv of p,t,p^2,t^2,pt + vertical scatter ----
    const int rgj = r0 - 5 + j;
    if (rgj >= 0 && rgj < IMG_H) {        // wave-uniform (r0, j uniform)
        const int sR = j & (RING - 1);
        const float* Lb = &B[sR][lane + 3];       // one base -> ds_read2
        v2f h01 = {0.f, 0.f};                     // {hp, ht}
        v2f h23 = {0.f, 0.f};                     // {hpp, htt}
        float hpt = 0.f;
        #pragma unroll
        for (int k = 0; k < 11; ++k) {
            const float w = G[k];
            const v2f wv = {w, w};
            v2f v;
            v.x = Lb[k];                          // p
            v.y = Lb[k + 80];                     // t   (read2 candidate)
            h01 = __builtin_elementwise_fma(wv, v, h01);     // pk_fma
            const v2f wab = wv * v;                          // pk_mul {wx,wy}
            h23 = __builtin_elementwise_fma(wab, v, h23);    // pk_fma
            hpt = fmaf(wab.x, v.y, hpt);                     // scalar fma
        }
        // vertical scatter: row j feeds outputs l = j-10..j, slot = l%11
#define SCAT(s) { constexpr int m = ((s) - PH + 21) % 11;                    \
                  constexpr float w = G[10 - m];                             \
                  const v2f wv = {w, w};                                     \
                  acc01[s] = __builtin_elementwise_fma(wv, h01, acc01[s]);   \
                  acc23[s] = __builtin_elementwise_fma(wv, h23, acc23[s]);   \
                  accpt[s] = fmaf(w, hpt, accpt[s]); }
        SCAT(0) SCAT(1) SCAT(2) SCAT(3) SCAT(4) SCAT(5)
        SCAT(6) SCAT(7) SCAT(8) SCAT(9) SCAT(10)
#undef SCAT
    }
    // (row-OOB: conv of zero rows contributes zero -> skip is identical.)

    // ---- emit completed output row l = j-10 (slot (PH+1)%11), then reset ----
    constexpr int SE = (PH + 1) % 11;
    const int l = j - 10;
    if (l >= 0 && l < TH) {                       // wave-uniform branch
        const float mp = acc01[SE].x, mt = acc01[SE].y;
        const float mpp = mp * mp, mtt = mt * mt, mpt = mp * mt;
        const float sp  = acc23[SE].x - mpp;
        const float st  = acc23[SE].y - mtt;
        const float spt = accpt[SE]   - mpt;
        const float num = (2.f * mpt + SSIM_C1) * (2.f * spt + SSIM_C2);
        const float den = (mpp + mtt + SSIM_C1) * (sp + st + SSIM_C2);
        lsum += num * __builtin_amdgcn_rcpf(den); // den >= C1*C2 > 0
    }
    acc01[SE] = (v2f){0.f, 0.f};
    acc23[SE] = (v2f){0.f, 0.f};
    accpt[SE] = 0.f;
}

__global__ __launch_bounds__(256, 2) void ssim_main(const float* __restrict__ pred,
                                                    const float* __restrict__ targ,
                                                    float* __restrict__ ws) {
    __shared__ float B[4][RING][LROW];    // [wave][slot][p|t]  = 20.0 KB
    __shared__ float wsum[4];

    const int tid  = threadIdx.x;
    const int lane = tid & 63;
    const int wid  = tid >> 6;

    // 6144 tiles = 8 col-strips x 8 row-bands x 96 planes; 4 waves/block.
    const int gt    = __builtin_amdgcn_readfirstlane(blockIdx.x * 4 + wid);
    const int c0    = (gt & 7) * TH;
    const int r0    = ((gt >> 3) & 7) * TH;
    const int plane = gt >> 6;
    // Window base: column c0-8 (16B-aligned since c0%64==0).
    const float* pplw = pred + (size_t)plane * (IMG_H * IMG_W) + (c0 - 8);
    const float* tplw = targ + (size_t)plane * (IMG_H * IMG_W) + (c0 - 8);

    float (*W)[LROW] = B[wid];

    // Lane covers window cols [4*lane, 4*lane+3] = global [c0-8+4*lane, +3].
    const int  lane4 = lane * 4;
    const int  gc0   = c0 - 8 + lane4;
    const bool lv    = (lane < 20) && (gc0 >= 0) && (gc0 <= IMG_W - 4);

    // Pre-zero LDS words of permanently masked lanes (edge strips only):
    // gload_lds never touches them, so they stay zero all kernel.
    if (lane < 20 && !lv) {
        #pragma unroll
        for (int s = 0; s < RING; ++s) {
            #pragma unroll
            for (int w = 0; w < 4; ++w) {
                W[s][lane4 + w]      = 0.f;       // p section
                W[s][80 + lane4 + w] = 0.f;       // t section
            }
        }
    }

    // Prologue: issue rows j=0..4 (global rows r0-5..r0-1, clamped) into
    // ring slots 0..4 = 10 VMEM ops.
    #pragma unroll
    for (int r = 0; r < 5; ++r) {
        const int rg  = max(r0 - 5 + r, 0);       // top clamp only (r0<=448)
        const float* ps = pplw + (size_t)rg * IMG_W + lane4;
        const float* ts = tplw + (size_t)rg * IMG_W + lane4;
        if (lv) {
            gload16(ps, &W[r][0]);
            gload16(ts, &W[r][80]);
        }
    }

    v2f   acc01[11];
    v2f   acc23[11];
    float accpt[11];
    #pragma unroll
    for (int s = 0; s < 11; ++s) {
        acc01[s] = (v2f){0.f, 0.f};
        acc23[s] = (v2f){0.f, 0.f};
        accpt[s] = 0.f;
    }

    float lsum = 0.f;

    for (int chunk = 0; chunk < NCHUNK; ++chunk) {
        const int j0 = chunk * 11;
#define P(n) phase<n>(pplw, tplw, r0, j0, lane4, W, lane, lv, \
                      acc01, acc23, accpt, lsum);
        P(0) P(1) P(2) P(3) P(4) P(5) P(6) P(7) P(8) P(9) P(10)
#undef P
    }

    // wave reduce -> one plain store per block into the workspace
    #pragma unroll
    for (int off = 32; off > 0; off >>= 1) lsum += __shfl_down(lsum, off);
    if (lane == 0) wsum[wid] = lsum;
    __syncthreads();
    if (tid == 0) ws[blockIdx.x] = wsum[0] + wsum[1] + wsum[2] + wsum[3];
}

__global__ __launch_bounds__(256) void ssim_finalize(const float* __restrict__ ws,
                                                     float* __restrict__ out) {
    __shared__ float wsum[4];
    const int tid  = threadIdx.x;
    const int lane = tid & 63;
    const int wid  = tid >> 6;
    float s = 0.f;
    #pragma unroll
    for (int i = 0; i < 6; ++i) s += ws[tid + 256 * i];   // 1536 = 6*256
    #pragma unroll
    for (int off = 32; off > 0; off >>= 1) s += __shfl_down(s, off);
    if (lane == 0) wsum[wid] = s;
    __syncthreads();
    if (tid == 0) {
        const float tot = wsum[0] + wsum[1] + wsum[2] + wsum[3];
        out[0] = 1.0f - tot * (1.0f / 25165824.0f);  // 1 - sum/(32*3*512*512)
    }
}

extern "C" void kernel_launch(void* const* d_in, const int* in_sizes, int n_in,
                              void* d_out, int out_size, void* d_ws, size_t ws_size,
                              hipStream_t stream) {
    (void)in_sizes; (void)n_in; (void)out_size; (void)ws_size;
    const float* pred = (const float*)d_in[0];
    const float* targ = (const float*)d_in[1];
    float* ws  = (float*)d_ws;          // 1536 floats of scratch
    float* out = (float*)d_out;

    ssim_main<<<dim3(1536), 256, 0, stream>>>(pred, targ, ws);
    ssim_finalize<<<1, 256, 0, stream>>>(ws, out);
}